// Round 4
// baseline (303.877 us; speedup 1.0000x reference)
//
#include <hip/hip_runtime.h>

// LSTMDecoder fused, transposed-MFMA formulation.
// All GEMMs computed as out^T = W'^T @ in^T with fp16 MFMA 16x16x32.
// MFMA N-dim = batch (16/tile), M-dim = output features, K = input features (128 = 4 kb of 32).
// C/D layout (m89-verified, dtype-independent): col = lane&15 (batch), row = (lane>>4)*4 + reg.
// B-frag slot (g=lane>>4, j): logical k = kmap(g,j) = j<4 ? 4g+j : 16+4g+(j-4).
// Same kmap used for prep-packed A-frags (weights) -> contraction correct for any true HW k-order,
// and stage outputs land exactly in next-stage B-frag slots (zero shuffles).

#define L2E 1.4426950408889634f

typedef _Float16 half8 __attribute__((ext_vector_type(8)));
typedef float f32x4 __attribute__((ext_vector_type(4)));

// blob region base offsets in HALF8 (8 x f16 = 16B) units
#define FWX0 0
#define FWX1 8192
#define FWH1 16384
#define FWX2 24576
#define FWH2 32768
#define FHFC 40960
#define FCFC 43008
#define FMID0 45056
#define FMID1 47104
#define FMID2 49152
#define FOUT1 51200
#define FOUT2 52992
#define FOUT3 55040
#define NBLOB_F16 442368   // 55296 half8 * 8

// ---------------- prep: pack fp32 weights -> fp16 A-fragment blob in d_ws ----------------
__global__ void lstm_prep(const float* __restrict__ Wx, const float* __restrict__ Wh,
                          const float* __restrict__ hfcW, const float* __restrict__ cfcW,
                          const float* __restrict__ midW, const float* __restrict__ o1W,
                          const float* __restrict__ o2W, const float* __restrict__ o3W,
                          _Float16* __restrict__ blob)
{
    int idx = blockIdx.x * 256 + threadIdx.x;
    if (idx >= NBLOB_F16) return;

    const float* src;
    int style;       // 0 = z-gate (512 cols, gate-packed, scaled), 1 = plain 128 cols, 2 = out (padded)
    int N = 0;
    int local;
    if      (idx < FWX1 * 8)  { src = Wx;           local = idx - FWX0 * 8;  style = 0; }
    else if (idx < FWH1 * 8)  { src = Wx + 65536;   local = idx - FWX1 * 8;  style = 0; }
    else if (idx < FWX2 * 8)  { src = Wh + 65536;   local = idx - FWH1 * 8;  style = 0; }
    else if (idx < FWH2 * 8)  { src = Wx + 131072;  local = idx - FWX2 * 8;  style = 0; }
    else if (idx < FHFC * 8)  { src = Wh + 131072;  local = idx - FWH2 * 8;  style = 0; }
    else if (idx < FCFC * 8)  { src = hfcW;         local = idx - FHFC * 8;  style = 1; }
    else if (idx < FMID0 * 8) { src = cfcW;         local = idx - FCFC * 8;  style = 1; }
    else if (idx < FMID1 * 8) { src = midW;         local = idx - FMID0 * 8; style = 1; }
    else if (idx < FMID2 * 8) { src = midW + 16384; local = idx - FMID1 * 8; style = 1; }
    else if (idx < FOUT1 * 8) { src = midW + 32768; local = idx - FMID2 * 8; style = 1; }
    else if (idx < FOUT2 * 8) { src = o1W;          local = idx - FOUT1 * 8; style = 2; N = 103; }
    else if (idx < FOUT3 * 8) { src = o2W;          local = idx - FOUT2 * 8; style = 2; N = 119; }
    else                      { src = o3W;          local = idx - FOUT3 * 8; style = 2; N = 11;  }

    int Mtile = local >> 11;          // 2048 f16 per Mtile (4 kb * 64 lanes * 8)
    int rem   = local & 2047;
    int kb    = rem >> 9;
    int lane  = (rem >> 3) & 63;
    int j     = rem & 7;
    int g = lane >> 4, m = lane & 15;
    int k = 32 * kb + ((j < 4) ? (4 * g + j) : (16 + 4 * g + (j - 4)));   // kmap

    float v;
    if (style == 0) {
        int ft = Mtile >> 2, gate = Mtile & 3;
        int n = gate * 128 + ft * 16 + m;
        float s = (gate == 2) ? (2.0f * L2E) : (-L2E);   // g-gate: tanh form, i/f/o: sigmoid form
        v = src[k * 512 + n] * s;
    } else if (style == 1) {
        v = src[k * 128 + Mtile * 16 + m];
    } else {
        int n = Mtile * 16 + m;
        v = (n < N) ? src[k * N + n] : 0.0f;
    }
    blob[idx] = (_Float16)v;
}

// ---------------- main fused kernel ----------------

// base: region offset in half8 units; frag = Mtile*4 + kb (64 half8 per frag)
__device__ __forceinline__ half8 ldA(const _Float16* __restrict__ blob, int base, int frag, int lane)
{
    return ((const half8*)blob)[base + frag * 64 + lane];
}

__device__ __forceinline__ half8 ldX(const float* __restrict__ xrow)
{
    const float4* p = (const float4*)xrow;
    float4 a = p[0];   // feats 32kb+4g+0..3
    float4 b = p[4];   // feats 32kb+16+4g+0..3
    half8 r;
    r[0] = (_Float16)a.x; r[1] = (_Float16)a.y; r[2] = (_Float16)a.z; r[3] = (_Float16)a.w;
    r[4] = (_Float16)b.x; r[5] = (_Float16)b.y; r[6] = (_Float16)b.z; r[7] = (_Float16)b.w;
    return r;
}

__device__ __forceinline__ float sigz(float z)   // 1 / (1 + 2^z)
{
    return __builtin_amdgcn_rcpf(1.0f + __builtin_amdgcn_exp2f(z));
}

#define MFMA16(A, B, C) __builtin_amdgcn_mfma_f32_16x16x32_f16(A, B, C, 0, 0, 0)

// stage A: h1,c1 = cell(x, 0, 0)  (skip f-gate and Wh0)
__device__ __forceinline__ void stageA(const _Float16* __restrict__ blob, const float* __restrict__ b3,
                                       const half8 (&xf)[4][2], half8 (&ho)[4][2], half8 (&co)[4][2],
                                       int lane, int rowg)
{
#pragma unroll
    for (int ft = 0; ft < 8; ++ft) {
        f32x4 ai[2], ag[2], ao[2];
#pragma unroll
        for (int bt = 0; bt < 2; ++bt) { ai[bt] = f32x4{0,0,0,0}; ag[bt] = f32x4{0,0,0,0}; ao[bt] = f32x4{0,0,0,0}; }
#pragma unroll
        for (int kb = 0; kb < 4; ++kb) {
            half8 A0 = ldA(blob, FWX0, (ft * 4 + 0) * 4 + kb, lane);
            half8 A2 = ldA(blob, FWX0, (ft * 4 + 2) * 4 + kb, lane);
            half8 A3 = ldA(blob, FWX0, (ft * 4 + 3) * 4 + kb, lane);
#pragma unroll
            for (int bt = 0; bt < 2; ++bt) {
                ai[bt] = MFMA16(A0, xf[kb][bt], ai[bt]);
                ag[bt] = MFMA16(A2, xf[kb][bt], ag[bt]);
                ao[bt] = MFMA16(A3, xf[kb][bt], ao[bt]);
            }
        }
        float4 bi4 = *(const float4*)(b3 + 0   + ft * 16 + 4 * rowg);
        float4 bg4 = *(const float4*)(b3 + 256 + ft * 16 + 4 * rowg);
        float4 bo4 = *(const float4*)(b3 + 384 + ft * 16 + 4 * rowg);
        float bi[4] = {bi4.x, bi4.y, bi4.z, bi4.w};
        float bg[4] = {bg4.x, bg4.y, bg4.z, bg4.w};
        float bo[4] = {bo4.x, bo4.y, bo4.z, bo4.w};
#pragma unroll
        for (int bt = 0; bt < 2; ++bt) {
#pragma unroll
            for (int r = 0; r < 4; ++r) {
                float si = sigz(ai[bt][r] - L2E * bi[r]);
                float tg = 1.0f - 2.0f * sigz(ag[bt][r] + 2.0f * L2E * bg[r]);
                float so = sigz(ao[bt][r] - L2E * bo[r]);
                float c  = si * tg;
                float h  = so * (1.0f - 2.0f * sigz(2.0f * L2E * c));
                ho[ft >> 1][bt][(ft & 1) * 4 + r] = (_Float16)h;
                co[ft >> 1][bt][(ft & 1) * 4 + r] = (_Float16)c;
            }
        }
    }
}

// generic LSTM stage: z = Wx'@x + Wh'@h + b  ->  h_out, c_out  (cprev packed fp16)
template <int L>
__device__ __forceinline__ void zstage(const _Float16* __restrict__ blob, const float* __restrict__ b3,
                                       int FX, int FH,
                                       const half8 (&xf)[4][2], const half8 (&hf)[4][2],
                                       const half8 (&cp)[4][2],
                                       half8 (&ho)[4][2], half8 (&co)[4][2],
                                       int lane, int rowg)
{
#pragma unroll
    for (int ft = 0; ft < 8; ++ft) {
        f32x4 ai[2], af[2], ag[2], ao[2];
#pragma unroll
        for (int bt = 0; bt < 2; ++bt) {
            ai[bt] = f32x4{0,0,0,0}; af[bt] = f32x4{0,0,0,0};
            ag[bt] = f32x4{0,0,0,0}; ao[bt] = f32x4{0,0,0,0};
        }
#pragma unroll
        for (int kb = 0; kb < 4; ++kb) {
            half8 A0 = ldA(blob, FX, (ft * 4 + 0) * 4 + kb, lane);
            half8 A1 = ldA(blob, FX, (ft * 4 + 1) * 4 + kb, lane);
            half8 A2 = ldA(blob, FX, (ft * 4 + 2) * 4 + kb, lane);
            half8 A3 = ldA(blob, FX, (ft * 4 + 3) * 4 + kb, lane);
#pragma unroll
            for (int bt = 0; bt < 2; ++bt) {
                ai[bt] = MFMA16(A0, xf[kb][bt], ai[bt]);
                af[bt] = MFMA16(A1, xf[kb][bt], af[bt]);
                ag[bt] = MFMA16(A2, xf[kb][bt], ag[bt]);
                ao[bt] = MFMA16(A3, xf[kb][bt], ao[bt]);
            }
            half8 B0 = ldA(blob, FH, (ft * 4 + 0) * 4 + kb, lane);
            half8 B1 = ldA(blob, FH, (ft * 4 + 1) * 4 + kb, lane);
            half8 B2 = ldA(blob, FH, (ft * 4 + 2) * 4 + kb, lane);
            half8 B3 = ldA(blob, FH, (ft * 4 + 3) * 4 + kb, lane);
#pragma unroll
            for (int bt = 0; bt < 2; ++bt) {
                ai[bt] = MFMA16(B0, hf[kb][bt], ai[bt]);
                af[bt] = MFMA16(B1, hf[kb][bt], af[bt]);
                ag[bt] = MFMA16(B2, hf[kb][bt], ag[bt]);
                ao[bt] = MFMA16(B3, hf[kb][bt], ao[bt]);
            }
        }
        const float* bb = b3 + L * 512;
        float4 bi4 = *(const float4*)(bb + 0   + ft * 16 + 4 * rowg);
        float4 bf4 = *(const float4*)(bb + 128 + ft * 16 + 4 * rowg);
        float4 bg4 = *(const float4*)(bb + 256 + ft * 16 + 4 * rowg);
        float4 bo4 = *(const float4*)(bb + 384 + ft * 16 + 4 * rowg);
        float bi[4] = {bi4.x, bi4.y, bi4.z, bi4.w};
        float bf[4] = {bf4.x, bf4.y, bf4.z, bf4.w};
        float bg[4] = {bg4.x, bg4.y, bg4.z, bg4.w};
        float bo[4] = {bo4.x, bo4.y, bo4.z, bo4.w};
#pragma unroll
        for (int bt = 0; bt < 2; ++bt) {
#pragma unroll
            for (int r = 0; r < 4; ++r) {
                float cprev = (float)cp[ft >> 1][bt][(ft & 1) * 4 + r];
                float si = sigz(ai[bt][r] - L2E * bi[r]);
                float sf = sigz(af[bt][r] - L2E * bf[r]);
                float tg = 1.0f - 2.0f * sigz(ag[bt][r] + 2.0f * L2E * bg[r]);
                float so = sigz(ao[bt][r] - L2E * bo[r]);
                float c  = sf * cprev + si * tg;
                float h  = so * (1.0f - 2.0f * sigz(2.0f * L2E * c));
                ho[ft >> 1][bt][(ft & 1) * 4 + r] = (_Float16)h;
                co[ft >> 1][bt][(ft & 1) * 4 + r] = (_Float16)c;
            }
        }
    }
}

// fc fusion: io = io + bfr@W + b   (elementwise add into packed fp16 io)
__device__ __forceinline__ void fcstage(const _Float16* __restrict__ blob, int FW,
                                        const float* __restrict__ fcb,
                                        const half8 (&bfr)[4][2], half8 (&io)[4][2],
                                        int lane, int rowg)
{
#pragma unroll
    for (int ft = 0; ft < 8; ++ft) {
        f32x4 acc[2];
#pragma unroll
        for (int bt = 0; bt < 2; ++bt) acc[bt] = f32x4{0,0,0,0};
#pragma unroll
        for (int kb = 0; kb < 4; ++kb) {
            half8 A = ldA(blob, FW, ft * 4 + kb, lane);
#pragma unroll
            for (int bt = 0; bt < 2; ++bt) acc[bt] = MFMA16(A, bfr[kb][bt], acc[bt]);
        }
        float4 b4 = *(const float4*)(fcb + ft * 16 + 4 * rowg);
        float bbv[4] = {b4.x, b4.y, b4.z, b4.w};
#pragma unroll
        for (int bt = 0; bt < 2; ++bt) {
#pragma unroll
            for (int r = 0; r < 4; ++r) {
                float v = acc[bt][r] + bbv[r] + (float)io[ft >> 1][bt][(ft & 1) * 4 + r];
                io[ft >> 1][bt][(ft & 1) * 4 + r] = (_Float16)v;
            }
        }
    }
}

// head: o = relu(h@midW + midb)@outW + outb ; scatter-store to [batch][rowlen]
template <int NMT>
__device__ __forceinline__ void head(const _Float16* __restrict__ blob, int FMID, int FOUT,
                                     const float* __restrict__ midb, const float* __restrict__ outb,
                                     int Nreal, float* __restrict__ outbase, int rowlen,
                                     const half8 (&hf)[4][2], half8 (&mfr)[4][2],
                                     int lane, int rowg, int col, int batch0)
{
#pragma unroll
    for (int ft = 0; ft < 8; ++ft) {
        f32x4 acc[2];
#pragma unroll
        for (int bt = 0; bt < 2; ++bt) acc[bt] = f32x4{0,0,0,0};
#pragma unroll
        for (int kb = 0; kb < 4; ++kb) {
            half8 A = ldA(blob, FMID, ft * 4 + kb, lane);
#pragma unroll
            for (int bt = 0; bt < 2; ++bt) acc[bt] = MFMA16(A, hf[kb][bt], acc[bt]);
        }
        float4 b4 = *(const float4*)(midb + ft * 16 + 4 * rowg);
        float mb[4] = {b4.x, b4.y, b4.z, b4.w};
#pragma unroll
        for (int bt = 0; bt < 2; ++bt) {
#pragma unroll
            for (int r = 0; r < 4; ++r) {
                float mv = fmaxf(acc[bt][r] + mb[r], 0.0f);
                mfr[ft >> 1][bt][(ft & 1) * 4 + r] = (_Float16)mv;
            }
        }
    }
#pragma unroll
    for (int Mt = 0; Mt < NMT; ++Mt) {
        f32x4 acc[2];
#pragma unroll
        for (int bt = 0; bt < 2; ++bt) acc[bt] = f32x4{0,0,0,0};
#pragma unroll
        for (int kb = 0; kb < 4; ++kb) {
            half8 A = ldA(blob, FOUT, Mt * 4 + kb, lane);
#pragma unroll
            for (int bt = 0; bt < 2; ++bt) acc[bt] = MFMA16(A, mfr[kb][bt], acc[bt]);
        }
#pragma unroll
        for (int bt = 0; bt < 2; ++bt) {
            int batch = batch0 + bt * 16 + col;
#pragma unroll
            for (int r = 0; r < 4; ++r) {
                int n = Mt * 16 + 4 * rowg + r;
                if (n < Nreal)
                    outbase[batch * rowlen + n] = acc[bt][r] + outb[n];
            }
        }
    }
}

__global__ __launch_bounds__(256, 2) void lstm_fused(
    const float* __restrict__ x, const float* __restrict__ b3,
    const float* __restrict__ hfc_b, const float* __restrict__ cfc_b,
    const float* __restrict__ mid_b, const float* __restrict__ o1b,
    const float* __restrict__ o2b, const float* __restrict__ o3b,
    const _Float16* __restrict__ blob, float* __restrict__ out)
{
    int tid = threadIdx.x;
    int lane = tid & 63;
    int wv = tid >> 6;
    int wave = blockIdx.x * 4 + wv;
    int batch0 = wave * 32;
    int rowg = lane >> 4, col = lane & 15;

    half8 xf[4][2], hA[4][2], cA[4][2], hB[4][2], cB[4][2], mfr[4][2];

#pragma unroll
    for (int kb = 0; kb < 4; ++kb)
#pragma unroll
        for (int bt = 0; bt < 2; ++bt)
            xf[kb][bt] = ldX(x + (size_t)(batch0 + bt * 16 + col) * 128 + 32 * kb + 4 * rowg);

    // stage 1: h1,c1  (hA,cA)
    stageA(blob, b3, xf, hA, cA, lane, rowg);
    // head 1 (uses h1)
    head<7>(blob, FMID0, FOUT1, mid_b, o1b, 103, out, 103, hA, mfr, lane, rowg, col, batch0);
    // stage 2: h2,c2  (hB,cB)
    zstage<1>(blob, b3, FWX1, FWH1, xf, hA, cA, hB, cB, lane, rowg);
    // fusion: hA <- h3_in = h1 + h2@hfc + hfc_b ; cA <- c3_in = c1 + c2@cfc + cfc_b
    fcstage(blob, FHFC, hfc_b, hB, hA, lane, rowg);
    fcstage(blob, FCFC, cfc_b, cB, cA, lane, rowg);
    // head 2 (uses h2, before hB is overwritten)
    head<8>(blob, FMID1, FOUT2, mid_b + 128, o2b, 119, out + (size_t)65536 * 103, 119, hB, mfr, lane, rowg, col, batch0);
    // stage 3: h3 (-> hB), c3 discarded (cB dead)
    zstage<2>(blob, b3, FWX2, FWH2, xf, hA, cA, hB, cB, lane, rowg);
    // head 3 (uses h3)
    head<1>(blob, FMID2, FOUT3, mid_b + 256, o3b, 11, out + (size_t)65536 * 222, 11, hB, mfr, lane, rowg, col, batch0);
}

extern "C" void kernel_launch(void* const* d_in, const int* in_sizes, int n_in,
                              void* d_out, int out_size, void* d_ws, size_t ws_size,
                              hipStream_t stream)
{
    const float* x     = (const float*)d_in[0];
    const float* Wx    = (const float*)d_in[1];
    const float* Wh    = (const float*)d_in[2];
    const float* b3    = (const float*)d_in[3];
    const float* hfcW  = (const float*)d_in[4];
    const float* hfc_b = (const float*)d_in[5];
    const float* cfcW  = (const float*)d_in[6];
    const float* cfc_b = (const float*)d_in[7];
    const float* midW  = (const float*)d_in[8];
    const float* mid_b = (const float*)d_in[9];
    const float* o1W   = (const float*)d_in[10];
    const float* o1b   = (const float*)d_in[11];
    const float* o2W   = (const float*)d_in[12];
    const float* o2b   = (const float*)d_in[13];
    const float* o3W   = (const float*)d_in[14];
    const float* o3b   = (const float*)d_in[15];
    float* out = (float*)d_out;

    if (ws_size < (size_t)NBLOB_F16 * sizeof(_Float16)) return;  // need ~884 KB scratch
    _Float16* blob = (_Float16*)d_ws;

    lstm_prep<<<(NBLOB_F16 + 255) / 256, 256, 0, stream>>>(Wx, Wh, hfcW, cfcW, midW, o1W, o2W, o3W, blob);
    lstm_fused<<<512, 256, 0, stream>>>(x, b3, hfc_b, cfc_b, mid_b, o1b, o2b, o3b, blob, out);
}